// Round 4
// baseline (278.580 us; speedup 1.0000x reference)
//
#include <hip/hip_runtime.h>
#include <stdint.h>

// Problem constants
#define M_TOK   16384        // 8 * 2048 tokens
#define EMBED   1024
#define FFN     4096
#define NQ      10

#define GK 4096
#define GN 1024
#define BK 64
#define NT (GK / BK)         // 64 K-tiles

typedef __attribute__((ext_vector_type(8))) short  bf16x8;
typedef __attribute__((ext_vector_type(4))) float  f32x4;
typedef __attribute__((ext_vector_type(8))) unsigned short u16x8;

static __device__ __forceinline__ unsigned short f2bf(float f) {
    union { float f; unsigned u; } v; v.f = f;
    unsigned r = v.u + 0x7FFF + ((v.u >> 16) & 1);   // round-to-nearest-even
    return (unsigned short)(r >> 16);
}

// ---------------------------------------------------------------------------
// Kernel 1: h[t][f] = relu( sum_i cos(x[t][i]) * cos(ry[i]) * w1[f][i] ) -> bf16
// ---------------------------------------------------------------------------
__global__ __launch_bounds__(256) void compute_h(
    const float* __restrict__ x, const float* __restrict__ ry,
    const float* __restrict__ w1, unsigned short* __restrict__ h)
{
    __shared__ float cq[32 * 16];    // 2 KB, stride 16 for alignment
    __shared__ float cry[NQ];

    const int tid = threadIdx.x;
    const int t0  = blockIdx.x * 32;
    const int fb  = blockIdx.y * 2048 + tid * 8;   // this thread's 8 f's

    if (tid < NQ) cry[tid] = cosf(ry[tid]);
    for (int idx = tid; idx < 32 * NQ; idx += 256) {
        int t = idx / NQ;
        int i = idx - t * NQ;
        cq[t * 16 + i] = cosf(x[(size_t)(t0 + t) * EMBED + i]);
    }
    __syncthreads();

    // premultiply w1 rows by cos(phi): 80 floats in registers
    float wf[8][NQ];
#pragma unroll
    for (int fi = 0; fi < 8; ++fi)
#pragma unroll
        for (int i = 0; i < NQ; ++i)
            wf[fi][i] = w1[(fb + fi) * NQ + i] * cry[i];

    for (int t = 0; t < 32; ++t) {
        const float4 c0 = *(const float4*)&cq[t * 16 + 0];
        const float4 c1 = *(const float4*)&cq[t * 16 + 4];
        const float2 c2 = *(const float2*)&cq[t * 16 + 8];
        u16x8 v;
#pragma unroll
        for (int fi = 0; fi < 8; ++fi) {
            float s = c0.x * wf[fi][0] + c0.y * wf[fi][1] + c0.z * wf[fi][2]
                    + c0.w * wf[fi][3] + c1.x * wf[fi][4] + c1.y * wf[fi][5]
                    + c1.z * wf[fi][6] + c1.w * wf[fi][7] + c2.x * wf[fi][8]
                    + c2.y * wf[fi][9];
            v[fi] = f2bf(fmaxf(s, 0.f));
        }
        *(u16x8*)(h + (size_t)(t0 + t) * FFN + fb) = v;
    }
}

// ---------------------------------------------------------------------------
// Kernel 2: w2 fp32 -> bf16.  4,194,304 elems, 8 per thread.
// ---------------------------------------------------------------------------
__global__ __launch_bounds__(256) void conv_w2(
    const float* __restrict__ w2, unsigned short* __restrict__ o)
{
    const int idx = (blockIdx.x * 256 + threadIdx.x) * 8;
    float4 a = *(const float4*)(w2 + idx);
    float4 b = *(const float4*)(w2 + idx + 4);
    u16x8 v;
    v[0] = f2bf(a.x); v[1] = f2bf(a.y); v[2] = f2bf(a.z); v[3] = f2bf(a.w);
    v[4] = f2bf(b.x); v[5] = f2bf(b.y); v[6] = f2bf(b.z); v[7] = f2bf(b.w);
    *(u16x8*)(o + idx) = v;
}

// ---------------------------------------------------------------------------
// Kernel 3: C[M][N] = A[M][K] * B[N][K]^T   (bf16 in, fp32 out)
//
// m201-faithful 8-phase / 2-K-tile iteration with COUNTED vmcnt (T3+T4+T5).
// 256x256 tile, 512 threads = 8 waves (2M x 4N), per-wave 128x64.
// BK=64, 128 B LDS rows, verified XOR chunk swizzle (0 conflicts).
//
// Iter t computes tile u=2t from buf0 (P1-P4) and v=2t+1 from buf1 (P5-P8),
// one C-quadrant x K=64 per phase. ds_reads per phase: {12,4,8,0}.
// Buf write windows (from read schedule: B read Pa+Pb, A read Pa+Pc):
//   buf-B free after Pb-end barrier, buf-A free after Pc-end barrier.
// Stage map (1 half-tile = 2 loads/thread per phase, m201 granularity):
//   P1: buf1.A-h0 <- A(v)      P5: buf0.A-h0 <- A(u+2)
//   P2: buf1.A-h1 <- A(v)      P6: buf0.A-h1 <- A(u+2)
//   P3: buf0.B-h0 <- B(u+2)    P7: buf1.B-h0 <- B(v+2)
//   P4: buf0.B-h1 <- B(u+2)    P8: buf1.B-h1 <- B(v+2)
//      + vmcnt(4)                 + vmcnt(4)
// vmcnt ledger (per wave, 2 loads/stage): at P4-end outstanding <=12
// (P7'',P8'' leftover + P1..P4); vmcnt(4) retires {B(v),A(v)} -> buf1 ready
// for P5. At P8-end <=12 (P3,P4 leftover + P5..P8); vmcnt(4) retires
// {B,A}(u+2) -> buf0 ready for next P1. NEVER drains to 0 in the loop; every
// stage has >=2-phase (~1600 cyc > ~900 HBM) coverage before its wait.
// Tail iters clamp stage offset to k=0: garbage lands only in regions whose
// reads are provably finished and never re-read; counts stay uniform.
// Each phase: reads|stage -> s_barrier -> lgkmcnt(0)+sched_barrier ->
// setprio(1) 16xMFMA setprio(0) [-> vmcnt(4)] -> s_barrier.
// ---------------------------------------------------------------------------
#define GL2LDS(g, l) \
    __builtin_amdgcn_global_load_lds( \
        (const __attribute__((address_space(1))) void*)(g), \
        (__attribute__((address_space(3))) void*)(l), 16, 0, 0)

__global__ __launch_bounds__(512, 2) void gemm_bt(
    const unsigned short* __restrict__ A,
    const unsigned short* __restrict__ B,
    float* __restrict__ C)
{
    __shared__ __align__(16) unsigned short As[2][256 * BK];   // 2 x 32 KB
    __shared__ __align__(16) unsigned short Bs[2][256 * BK];   // 2 x 32 KB

    const int tid  = threadIdx.x;
    const int wv   = tid >> 6;         // 0..7
    const int lane = tid & 63;
    const int wm   = wv >> 2;          // 0..1  (M half)
    const int wn   = wv & 3;           // 0..3  (N quarter)

    const int bid = blockIdx.x;
    const int wg  = (bid & 7) * 32 + (bid >> 3);   // XCD-chunked remap
    const int m0  = (wg >> 2) * 256;               // 64 m-blocks
    const int n0  = (wg & 3) * 256;                // 4 n-blocks

    // staging: per half-tile (128 rows) each wave covers 16 rows as 2 loads
    // of 8 rows; lane -> row lane>>3, chunk (lane&7)^(lane>>3) (XOR swizzle)
    const int srow8 = lane >> 3;
    const int schk  = (lane & 7) ^ srow8;
    const char* ag = (const char*)A +
        ((size_t)(m0 + wv * 16 + srow8) * GK + schk * 8) * 2;
    const char* bg = (const char*)B +
        ((size_t)(n0 + wv * 16 + srow8) * GK + schk * 8) * 2;
    const size_t ROW8 = (size_t)8 * GK * 2;     // 8 rows in global bytes
    const size_t HALF = (size_t)128 * GK * 2;   // 128 rows in global bytes

#define STAGE_A(buf, half, ko) do { \
    GL2LDS(ag + (ko) + (half) * HALF,        (char*)As[buf] + ((half) * 128 + wv * 16) * 128); \
    GL2LDS(ag + (ko) + (half) * HALF + ROW8, (char*)As[buf] + ((half) * 128 + wv * 16 + 8) * 128); \
} while (0)
#define STAGE_B(buf, half, ko) do { \
    GL2LDS(bg + (ko) + (half) * HALF,        (char*)Bs[buf] + ((half) * 128 + wv * 16) * 128); \
    GL2LDS(bg + (ko) + (half) * HALF + ROW8, (char*)Bs[buf] + ((half) * 128 + wv * 16 + 8) * 128); \
} while (0)

    // fragment read coordinates (verified layout)
    const int rr  = lane & 15;
    const int fsw = lane & 7;
    const int cc  = lane >> 4;
#define CHOFF(s) ((((s) * 4 + cc) ^ fsw) * 16)
#define AFRAGP(P, mh, i, s) (*(const bf16x8*)((P) + (wm * 128 + (mh) * 64 + (i) * 16 + rr) * 128 + CHOFF(s)))
#define BFRAGP(P, nh, j, s) (*(const bf16x8*)((P) + (wn * 64 + (nh) * 32 + (j) * 16 + rr) * 128 + CHOFF(s)))

#define LEADSYNC do { \
    __builtin_amdgcn_s_barrier(); \
    asm volatile("s_waitcnt lgkmcnt(0)" ::: "memory"); \
    __builtin_amdgcn_sched_barrier(0); \
} while (0)

    f32x4 acc[8][4] = {};

#define MFMA16(I0, J0, AF, BF) do { \
    __builtin_amdgcn_s_setprio(1); \
    _Pragma("unroll") \
    for (int s_ = 0; s_ < 2; ++s_) \
        _Pragma("unroll") \
        for (int i_ = 0; i_ < 4; ++i_) \
            _Pragma("unroll") \
            for (int j_ = 0; j_ < 2; ++j_) \
                acc[(I0) + i_][(J0) + j_] = __builtin_amdgcn_mfma_f32_16x16x32_bf16( \
                    AF[s_][i_], BF[s_][j_], acc[(I0) + i_][(J0) + j_], 0, 0, 0); \
    __builtin_amdgcn_s_setprio(0); \
} while (0)

    // prologue: buf0 <- tile0 (B0,B1,A0,A1), buf1 <- tile1 (B0,B1 only; its
    // A halves are staged at P1,P2 of iter 0). vmcnt(4) keeps tile1's B in
    // flight, retires all of tile0 -> identical to steady state.
    STAGE_B(0, 0, 0); STAGE_B(0, 1, 0);
    STAGE_A(0, 0, 0); STAGE_A(0, 1, 0);
    STAGE_B(1, 0, 128); STAGE_B(1, 1, 128);
    asm volatile("s_waitcnt vmcnt(4)" ::: "memory");
    __builtin_amdgcn_s_barrier();

#pragma unroll 1
    for (int t = 0; t < NT / 2; ++t) {
        const size_t kov = (size_t)(2 * t + 1) * 128;                      // tile v (real)
        const size_t ko2 = (2 * t + 2 < NT) ? (size_t)(2 * t + 2) * 128 : 0;
        const size_t ko3 = (2 * t + 3 < NT) ? (size_t)(2 * t + 3) * 128 : 0;

        bf16x8 afr[2][4], b0r[2][2], b1r[2][2];

        // ================= tile u = 2t  (buf0) =========================
        {
            const char* At = (const char*)As[0];
            const char* Bt = (const char*)Bs[0];

            // P1: read B0,A0 | stage buf1.A-h0 <- A(v)
#pragma unroll
            for (int s = 0; s < 2; ++s) {
#pragma unroll
                for (int j = 0; j < 2; ++j) b0r[s][j] = BFRAGP(Bt, 0, j, s);
#pragma unroll
                for (int i = 0; i < 4; ++i) afr[s][i] = AFRAGP(At, 0, i, s);
            }
            STAGE_A(1, 0, kov);
            LEADSYNC;
            MFMA16(0, 0, afr, b0r);
            __builtin_amdgcn_s_barrier();

            // P2: read B1 | stage buf1.A-h1 <- A(v)
#pragma unroll
            for (int s = 0; s < 2; ++s)
#pragma unroll
                for (int j = 0; j < 2; ++j) b1r[s][j] = BFRAGP(Bt, 1, j, s);
            STAGE_A(1, 1, kov);
            LEADSYNC;
            MFMA16(0, 2, afr, b1r);
            __builtin_amdgcn_s_barrier();

            // P3: read A1 | stage buf0.B-h0 <- B(u+2)
#pragma unroll
            for (int s = 0; s < 2; ++s)
#pragma unroll
                for (int i = 0; i < 4; ++i) afr[s][i] = AFRAGP(At, 1, i, s);
            STAGE_B(0, 0, ko2);
            LEADSYNC;
            MFMA16(4, 2, afr, b1r);
            __builtin_amdgcn_s_barrier();

            // P4: no reads | stage buf0.B-h1 <- B(u+2) | vmcnt(4)
            STAGE_B(0, 1, ko2);
            LEADSYNC;
            MFMA16(4, 0, afr, b0r);
            asm volatile("s_waitcnt vmcnt(4)" ::: "memory");
            __builtin_amdgcn_s_barrier();
        }

        // ================= tile v = 2t+1  (buf1) =======================
        {
            const char* At = (const char*)As[1];
            const char* Bt = (const char*)Bs[1];

            // P5: read B0,A0 | stage buf0.A-h0 <- A(u+2)
#pragma unroll
            for (int s = 0; s < 2; ++s) {
#pragma unroll
                for (int j = 0; j < 2; ++j) b0r[s][j] = BFRAGP(Bt, 0, j, s);
#pragma unroll
                for (int i = 0; i < 4; ++i) afr[s][i] = AFRAGP(At, 0, i, s);
            }
            STAGE_A(0, 0, ko2);
            LEADSYNC;
            MFMA16(0, 0, afr, b0r);
            __builtin_amdgcn_s_barrier();

            // P6: read B1 | stage buf0.A-h1 <- A(u+2)
#pragma unroll
            for (int s = 0; s < 2; ++s)
#pragma unroll
                for (int j = 0; j < 2; ++j) b1r[s][j] = BFRAGP(Bt, 1, j, s);
            STAGE_A(0, 1, ko2);
            LEADSYNC;
            MFMA16(0, 2, afr, b1r);
            __builtin_amdgcn_s_barrier();

            // P7: read A1 | stage buf1.B-h0 <- B(v+2)
#pragma unroll
            for (int s = 0; s < 2; ++s)
#pragma unroll
                for (int i = 0; i < 4; ++i) afr[s][i] = AFRAGP(At, 1, i, s);
            STAGE_B(1, 0, ko3);
            LEADSYNC;
            MFMA16(4, 2, afr, b1r);
            __builtin_amdgcn_s_barrier();

            // P8: no reads | stage buf1.B-h1 <- B(v+2) | vmcnt(4)
            STAGE_B(1, 1, ko3);
            LEADSYNC;
            MFMA16(4, 0, afr, b0r);
            asm volatile("s_waitcnt vmcnt(4)" ::: "memory");
            __builtin_amdgcn_s_barrier();
        }
    }

    // drain the <=4 tail garbage stages before epilogue
    asm volatile("s_waitcnt vmcnt(0)" ::: "memory");

    // epilogue: C/D layout col = lane&15, row = (lane>>4)*4 + reg
    const int cn = lane & 15;
    const int rb = (lane >> 4) * 4;
#pragma unroll
    for (int i = 0; i < 8; ++i)
#pragma unroll
        for (int j = 0; j < 4; ++j)
#pragma unroll
            for (int r = 0; r < 4; ++r) {
                const int m = m0 + wm * 128 + i * 16 + rb + r;
                const int n = n0 + wn * 64 + j * 16 + cn;
                C[(size_t)m * GN + n] = acc[i][j][r];
            }
}

// ---------------------------------------------------------------------------
extern "C" void kernel_launch(void* const* d_in, const int* in_sizes, int n_in,
                              void* d_out, int out_size, void* d_ws, size_t ws_size,
                              hipStream_t stream) {
    const float* x  = (const float*)d_in[0];
    const float* ry = (const float*)d_in[1];
    const float* w1 = (const float*)d_in[2];
    const float* w2 = (const float*)d_in[3];
    float* out = (float*)d_out;

    unsigned short* h   = (unsigned short*)d_ws;                       // 128 MiB
    unsigned short* w2b = (unsigned short*)((char*)d_ws +
                           (size_t)M_TOK * FFN * sizeof(unsigned short));

    compute_h<<<dim3(512, 2), 256, 0, stream>>>(x, ry, w1, h);
    conv_w2<<<dim3((EMBED * FFN) / (256 * 8)), 256, 0, stream>>>(w2, w2b);
    gemm_bt<<<dim3(256), 512, 0, stream>>>(h, w2b, out);
}

// Round 5
// 268.050 us; speedup vs baseline: 1.0393x; 1.0393x over previous
//
#include <hip/hip_runtime.h>
#include <stdint.h>

// Problem constants
#define M_TOK   16384        // 8 * 2048 tokens
#define EMBED   1024
#define FFN     4096
#define NQ      10

#define GK 4096
#define GN 1024
#define BK 64
#define NT (GK / BK)         // 64 K-tiles

typedef __attribute__((ext_vector_type(8))) short  bf16x8;
typedef __attribute__((ext_vector_type(4))) float  f32x4;
typedef __attribute__((ext_vector_type(8))) unsigned short u16x8;

static __device__ __forceinline__ unsigned short f2bf(float f) {
    union { float f; unsigned u; } v; v.f = f;
    unsigned r = v.u + 0x7FFF + ((v.u >> 16) & 1);   // round-to-nearest-even
    return (unsigned short)(r >> 16);
}

// ---------------------------------------------------------------------------
// Kernel 0: w1cT[i][f] = w1[f][i] * cos(ry[i])   (transpose + premultiply)
// 160 KB one-shot; reads 40 B contiguous per thread, writes coalesced.
// ---------------------------------------------------------------------------
__global__ __launch_bounds__(256) void prep_w1(
    const float* __restrict__ w1, const float* __restrict__ ry,
    float* __restrict__ w1cT)
{
    __shared__ float cry[16];
    if (threadIdx.x < NQ) cry[threadIdx.x] = cosf(ry[threadIdx.x]);
    __syncthreads();
    const int f = blockIdx.x * 256 + threadIdx.x;   // 0..4095
#pragma unroll
    for (int i = 0; i < NQ; ++i)
        w1cT[i * FFN + f] = w1[f * NQ + i] * cry[i];
}

// ---------------------------------------------------------------------------
// Kernel 1: h[t][f] = relu( sum_i cos(x[t][i]) * w1cT[i][f] ) -> bf16
// w1 is consumed via the TRANSPOSED premultiplied copy: wf[fi][i] loads are
// 20 coalesced float4 per thread (lane-adjacent f), replacing 80 scalar
// 320B-stride loads (64 cache lines per wave-instr, ~2.7 GB L2 traffic).
// ---------------------------------------------------------------------------
__global__ __launch_bounds__(256) void compute_h(
    const float* __restrict__ x, const float* __restrict__ w1cT,
    unsigned short* __restrict__ h)
{
    __shared__ float cq[32 * 16];    // 2 KB, stride 16 for alignment

    const int tid = threadIdx.x;
    const int t0  = blockIdx.x * 32;
    const int fb  = blockIdx.y * 2048 + tid * 8;   // this thread's 8 f's

    for (int idx = tid; idx < 32 * NQ; idx += 256) {
        int t = idx / NQ;
        int i = idx - t * NQ;
        cq[t * 16 + i] = cosf(x[(size_t)(t0 + t) * EMBED + i]);
    }
    __syncthreads();

    // wf[fi][i] = w1cT[i][fb+fi]: coalesced float4 pairs
    float wf[8][NQ];
#pragma unroll
    for (int i = 0; i < NQ; ++i) {
        const float4 lo = *(const float4*)(w1cT + (size_t)i * FFN + fb);
        const float4 hi = *(const float4*)(w1cT + (size_t)i * FFN + fb + 4);
        wf[0][i] = lo.x; wf[1][i] = lo.y; wf[2][i] = lo.z; wf[3][i] = lo.w;
        wf[4][i] = hi.x; wf[5][i] = hi.y; wf[6][i] = hi.z; wf[7][i] = hi.w;
    }

    for (int t = 0; t < 32; ++t) {
        const float4 c0 = *(const float4*)&cq[t * 16 + 0];
        const float4 c1 = *(const float4*)&cq[t * 16 + 4];
        const float2 c2 = *(const float2*)&cq[t * 16 + 8];
        u16x8 v;
#pragma unroll
        for (int fi = 0; fi < 8; ++fi) {
            float s = c0.x * wf[fi][0] + c0.y * wf[fi][1] + c0.z * wf[fi][2]
                    + c0.w * wf[fi][3] + c1.x * wf[fi][4] + c1.y * wf[fi][5]
                    + c1.z * wf[fi][6] + c1.w * wf[fi][7] + c2.x * wf[fi][8]
                    + c2.y * wf[fi][9];
            v[fi] = f2bf(fmaxf(s, 0.f));
        }
        *(u16x8*)(h + (size_t)(t0 + t) * FFN + fb) = v;
    }
}

// ---------------------------------------------------------------------------
// Kernel 2: w2 fp32 -> bf16.  4,194,304 elems, 8 per thread.
// ---------------------------------------------------------------------------
__global__ __launch_bounds__(256) void conv_w2(
    const float* __restrict__ w2, unsigned short* __restrict__ o)
{
    const int idx = (blockIdx.x * 256 + threadIdx.x) * 8;
    float4 a = *(const float4*)(w2 + idx);
    float4 b = *(const float4*)(w2 + idx + 4);
    u16x8 v;
    v[0] = f2bf(a.x); v[1] = f2bf(a.y); v[2] = f2bf(a.z); v[3] = f2bf(a.w);
    v[4] = f2bf(b.x); v[5] = f2bf(b.y); v[6] = f2bf(b.z); v[7] = f2bf(b.w);
    *(u16x8*)(o + idx) = v;
}

// ---------------------------------------------------------------------------
// Kernel 3: C[M][N] = A[M][K] * B[N][K]^T   (bf16 in, fp32 out)
// R3 version (best measured: 133.5 us). 4-phase-per-K-tile schedule,
// 256x256 tile, 512 threads = 8 waves (2M x 4N), per-wave 128x64.
// BK=64, 128 B LDS rows, verified XOR chunk swizzle (0 conflicts).
// ---------------------------------------------------------------------------
#define GL2LDS(g, l) \
    __builtin_amdgcn_global_load_lds( \
        (const __attribute__((address_space(1))) void*)(g), \
        (__attribute__((address_space(3))) void*)(l), 16, 0, 0)

__global__ __launch_bounds__(512, 2) void gemm_bt(
    const unsigned short* __restrict__ A,
    const unsigned short* __restrict__ B,
    float* __restrict__ C)
{
    __shared__ __align__(16) unsigned short As[2][256 * BK];   // 2 x 32 KB
    __shared__ __align__(16) unsigned short Bs[2][256 * BK];   // 2 x 32 KB

    const int tid  = threadIdx.x;
    const int wv   = tid >> 6;         // 0..7
    const int lane = tid & 63;
    const int wm   = wv >> 2;          // 0..1  (M half)
    const int wn   = wv & 3;           // 0..3  (N quarter)

    const int bid = blockIdx.x;
    const int wg  = (bid & 7) * 32 + (bid >> 3);   // XCD-chunked remap
    const int m0  = (wg >> 2) * 256;               // 64 m-blocks
    const int n0  = (wg & 3) * 256;                // 4 n-blocks

    // staging: per half-tile (128 rows), wave wv covers 16 rows as 2 loads of
    // 8 rows; lane -> row lane>>3, chunk (lane&7)^(lane>>3) (XOR swizzle).
    const int srow8 = lane >> 3;
    const int schk  = (lane & 7) ^ srow8;
    const char* ag = (const char*)A +
        ((size_t)(m0 + wv * 16 + srow8) * GK + schk * 8) * 2;
    const char* bg = (const char*)B +
        ((size_t)(n0 + wv * 16 + srow8) * GK + schk * 8) * 2;
    const size_t ROW8 = (size_t)8 * GK * 2;     // 8 rows in global bytes
    const size_t HALF = (size_t)128 * GK * 2;   // 128 rows in global bytes

#define STAGE_A(buf, half, ko) do { \
    GL2LDS(ag + (ko) + (half) * HALF,        (char*)As[buf] + ((half) * 128 + wv * 16) * 128); \
    GL2LDS(ag + (ko) + (half) * HALF + ROW8, (char*)As[buf] + ((half) * 128 + wv * 16 + 8) * 128); \
} while (0)
#define STAGE_B(buf, half, ko) do { \
    GL2LDS(bg + (ko) + (half) * HALF,        (char*)Bs[buf] + ((half) * 128 + wv * 16) * 128); \
    GL2LDS(bg + (ko) + (half) * HALF + ROW8, (char*)Bs[buf] + ((half) * 128 + wv * 16 + 8) * 128); \
} while (0)

    // fragment read coordinates (verified layout)
    const int rr  = lane & 15;
    const int fsw = lane & 7;
    const int cc  = lane >> 4;
#define CHOFF(s) ((((s) * 4 + cc) ^ fsw) * 16)
#define AFRAG(mh, i, s) (*(const bf16x8*)(At + (wm * 128 + (mh) * 64 + (i) * 16 + rr) * 128 + CHOFF(s)))
#define BFRAG(nh, j, s) (*(const bf16x8*)(Bt + (wn * 64 + (nh) * 32 + (j) * 16 + rr) * 128 + CHOFF(s)))

    f32x4 acc[8][4] = {};

    // prologue: stage tile 0 (all four halves), drain, publish
    STAGE_A(0, 0, 0); STAGE_A(0, 1, 0);
    STAGE_B(0, 0, 0); STAGE_B(0, 1, 0);
    asm volatile("s_waitcnt vmcnt(0)" ::: "memory");
    __builtin_amdgcn_s_barrier();

#pragma unroll 1
    for (int T = 0; T < NT; ++T) {
        const char* At = (const char*)As[T & 1];
        const char* Bt = (const char*)Bs[T & 1];
        const int nb   = (T + 1) & 1;
        const size_t ko = (size_t)(T + 1) * 128;   // K byte offset of tile T+1
        const bool st  = (T + 1 < NT);

        bf16x8 afr[2][4];   // current A half fragments [s][i]
        bf16x8 b0r[2][2];   // B nh0 [s][j]
        bf16x8 b1r[2][2];   // B nh1 [s][j]

        // ---- P1: Q(mh0, nh0) | stage A(T+1) both halves ----------------
#pragma unroll
        for (int s = 0; s < 2; ++s) {
#pragma unroll
            for (int j = 0; j < 2; ++j) b0r[s][j] = BFRAG(0, j, s);
#pragma unroll
            for (int i = 0; i < 4; ++i) afr[s][i] = AFRAG(0, i, s);
        }
        if (st) { STAGE_A(nb, 0, ko); STAGE_A(nb, 1, ko); }
        __builtin_amdgcn_s_barrier();
        asm volatile("s_waitcnt lgkmcnt(0)" ::: "memory");
        __builtin_amdgcn_sched_barrier(0);
        __builtin_amdgcn_s_setprio(1);
#pragma unroll
        for (int s = 0; s < 2; ++s)
#pragma unroll
            for (int i = 0; i < 4; ++i)
#pragma unroll
                for (int j = 0; j < 2; ++j)
                    acc[i][j] = __builtin_amdgcn_mfma_f32_16x16x32_bf16(
                        afr[s][i], b0r[s][j], acc[i][j], 0, 0, 0);
        __builtin_amdgcn_s_setprio(0);
        __builtin_amdgcn_s_barrier();

        // ---- P2: Q(mh0, nh1) | stage B(T+1) both halves ----------------
#pragma unroll
        for (int s = 0; s < 2; ++s)
#pragma unroll
            for (int j = 0; j < 2; ++j) b1r[s][j] = BFRAG(1, j, s);
        if (st) { STAGE_B(nb, 0, ko); STAGE_B(nb, 1, ko); }
        __builtin_amdgcn_s_barrier();
        asm volatile("s_waitcnt lgkmcnt(0)" ::: "memory");
        __builtin_amdgcn_sched_barrier(0);
        __builtin_amdgcn_s_setprio(1);
#pragma unroll
        for (int s = 0; s < 2; ++s)
#pragma unroll
            for (int i = 0; i < 4; ++i)
#pragma unroll
                for (int j = 0; j < 2; ++j)
                    acc[i][2 + j] = __builtin_amdgcn_mfma_f32_16x16x32_bf16(
                        afr[s][i], b1r[s][j], acc[i][2 + j], 0, 0, 0);
        __builtin_amdgcn_s_setprio(0);
        __builtin_amdgcn_s_barrier();

        // ---- P3: Q(mh1, nh1) -------------------------------------------
#pragma unroll
        for (int s = 0; s < 2; ++s)
#pragma unroll
            for (int i = 0; i < 4; ++i) afr[s][i] = AFRAG(1, i, s);
        __builtin_amdgcn_s_barrier();
        asm volatile("s_waitcnt lgkmcnt(0)" ::: "memory");
        __builtin_amdgcn_sched_barrier(0);
        __builtin_amdgcn_s_setprio(1);
#pragma unroll
        for (int s = 0; s < 2; ++s)
#pragma unroll
            for (int i = 0; i < 4; ++i)
#pragma unroll
                for (int j = 0; j < 2; ++j)
                    acc[4 + i][2 + j] = __builtin_amdgcn_mfma_f32_16x16x32_bf16(
                        afr[s][i], b1r[s][j], acc[4 + i][2 + j], 0, 0, 0);
        __builtin_amdgcn_s_setprio(0);
        __builtin_amdgcn_s_barrier();

        // ---- P4: Q(mh1, nh0) -- no new reads ---------------------------
        __builtin_amdgcn_s_setprio(1);
#pragma unroll
        for (int s = 0; s < 2; ++s)
#pragma unroll
            for (int i = 0; i < 4; ++i)
#pragma unroll
                for (int j = 0; j < 2; ++j)
                    acc[4 + i][j] = __builtin_amdgcn_mfma_f32_16x16x32_bf16(
                        afr[s][i], b0r[s][j], acc[4 + i][j], 0, 0, 0);
        __builtin_amdgcn_s_setprio(0);
        // retire T+1's stages (issued >=2 phases ago) and publish
        asm volatile("s_waitcnt vmcnt(0)" ::: "memory");
        __builtin_amdgcn_s_barrier();
    }

    // epilogue: C/D layout col = lane&15, row = (lane>>4)*4 + reg
    const int cn = lane & 15;
    const int rb = (lane >> 4) * 4;
#pragma unroll
    for (int i = 0; i < 8; ++i)
#pragma unroll
        for (int j = 0; j < 4; ++j)
#pragma unroll
            for (int r = 0; r < 4; ++r) {
                const int m = m0 + wm * 128 + i * 16 + rb + r;
                const int n = n0 + wn * 64 + j * 16 + cn;
                C[(size_t)m * GN + n] = acc[i][j][r];
            }
}

// ---------------------------------------------------------------------------
extern "C" void kernel_launch(void* const* d_in, const int* in_sizes, int n_in,
                              void* d_out, int out_size, void* d_ws, size_t ws_size,
                              hipStream_t stream) {
    const float* x  = (const float*)d_in[0];
    const float* ry = (const float*)d_in[1];
    const float* w1 = (const float*)d_in[2];
    const float* w2 = (const float*)d_in[3];
    float* out = (float*)d_out;

    unsigned short* h   = (unsigned short*)d_ws;                       // 128 MiB
    unsigned short* w2b = (unsigned short*)((char*)d_ws +
                           (size_t)M_TOK * FFN * sizeof(unsigned short));
    // w1cT (160 KB) overlays the w2b region: prep_w1 -> compute_h consume it
    // BEFORE conv_w2 overwrites the region (same-stream serialization).
    float* w1cT = (float*)w2b;

    prep_w1<<<dim3(FFN / 256), 256, 0, stream>>>(w1, ry, w1cT);
    compute_h<<<dim3(512, 2), 256, 0, stream>>>(x, w1cT, h);
    conv_w2<<<dim3((EMBED * FFN) / (256 * 8)), 256, 0, stream>>>(w2, w2b);
    gemm_bt<<<dim3(256), 512, 0, stream>>>(h, w2b, out);
}

// Round 6
// 255.526 us; speedup vs baseline: 1.0902x; 1.0490x over previous
//
#include <hip/hip_runtime.h>
#include <stdint.h>

// Problem constants
#define M_TOK   16384        // 8 * 2048 tokens
#define EMBED   1024
#define FFN     4096
#define NQ      10

#define GK 4096
#define GN 1024
#define BK 64
#define NT (GK / BK)         // 64 K-tiles

typedef __attribute__((ext_vector_type(8))) short  bf16x8;
typedef __attribute__((ext_vector_type(4))) float  f32x4;
typedef __attribute__((ext_vector_type(8))) unsigned short u16x8;

static __device__ __forceinline__ unsigned short f2bf(float f) {
    union { float f; unsigned u; } v; v.f = f;
    unsigned r = v.u + 0x7FFF + ((v.u >> 16) & 1);   // round-to-nearest-even
    return (unsigned short)(r >> 16);
}

// ---------------------------------------------------------------------------
// Kernel 0: w1cT[i][f] = w1[f][i] * cos(ry[i])   (transpose + premultiply)
// ---------------------------------------------------------------------------
__global__ __launch_bounds__(256) void prep_w1(
    const float* __restrict__ w1, const float* __restrict__ ry,
    float* __restrict__ w1cT)
{
    __shared__ float cry[16];
    if (threadIdx.x < NQ) cry[threadIdx.x] = cosf(ry[threadIdx.x]);
    __syncthreads();
    const int f = blockIdx.x * 256 + threadIdx.x;   // 0..4095
#pragma unroll
    for (int i = 0; i < NQ; ++i)
        w1cT[i * FFN + f] = w1[f * NQ + i] * cry[i];
}

// ---------------------------------------------------------------------------
// Kernel 1: h[t][f] = relu( sum_i cos(x[t][i]) * w1cT[i][f] ) -> bf16
// (frozen from R5 -- "rest" time is insensitive to this kernel's form)
// ---------------------------------------------------------------------------
__global__ __launch_bounds__(256) void compute_h(
    const float* __restrict__ x, const float* __restrict__ w1cT,
    unsigned short* __restrict__ h)
{
    __shared__ float cq[32 * 16];    // 2 KB, stride 16 for alignment

    const int tid = threadIdx.x;
    const int t0  = blockIdx.x * 32;
    const int fb  = blockIdx.y * 2048 + tid * 8;   // this thread's 8 f's

    for (int idx = tid; idx < 32 * NQ; idx += 256) {
        int t = idx / NQ;
        int i = idx - t * NQ;
        cq[t * 16 + i] = cosf(x[(size_t)(t0 + t) * EMBED + i]);
    }
    __syncthreads();

    float wf[8][NQ];
#pragma unroll
    for (int i = 0; i < NQ; ++i) {
        const float4 lo = *(const float4*)(w1cT + (size_t)i * FFN + fb);
        const float4 hi = *(const float4*)(w1cT + (size_t)i * FFN + fb + 4);
        wf[0][i] = lo.x; wf[1][i] = lo.y; wf[2][i] = lo.z; wf[3][i] = lo.w;
        wf[4][i] = hi.x; wf[5][i] = hi.y; wf[6][i] = hi.z; wf[7][i] = hi.w;
    }

    for (int t = 0; t < 32; ++t) {
        const float4 c0 = *(const float4*)&cq[t * 16 + 0];
        const float4 c1 = *(const float4*)&cq[t * 16 + 4];
        const float2 c2 = *(const float2*)&cq[t * 16 + 8];
        u16x8 v;
#pragma unroll
        for (int fi = 0; fi < 8; ++fi) {
            float s = c0.x * wf[fi][0] + c0.y * wf[fi][1] + c0.z * wf[fi][2]
                    + c0.w * wf[fi][3] + c1.x * wf[fi][4] + c1.y * wf[fi][5]
                    + c1.z * wf[fi][6] + c1.w * wf[fi][7] + c2.x * wf[fi][8]
                    + c2.y * wf[fi][9];
            v[fi] = f2bf(fmaxf(s, 0.f));
        }
        *(u16x8*)(h + (size_t)(t0 + t) * FFN + fb) = v;
    }
}

// ---------------------------------------------------------------------------
// Kernel 2: w2 fp32 -> bf16.  4,194,304 elems, 8 per thread.
// ---------------------------------------------------------------------------
__global__ __launch_bounds__(256) void conv_w2(
    const float* __restrict__ w2, unsigned short* __restrict__ o)
{
    const int idx = (blockIdx.x * 256 + threadIdx.x) * 8;
    float4 a = *(const float4*)(w2 + idx);
    float4 b = *(const float4*)(w2 + idx + 4);
    u16x8 v;
    v[0] = f2bf(a.x); v[1] = f2bf(a.y); v[2] = f2bf(a.z); v[3] = f2bf(a.w);
    v[4] = f2bf(b.x); v[5] = f2bf(b.y); v[6] = f2bf(b.z); v[7] = f2bf(b.w);
    *(u16x8*)(o + idx) = v;
}

// ---------------------------------------------------------------------------
// Kernel 3: C[M][N] = A[M][K] * B[N][K]^T   (bf16 in, fp32 out)
//
// Register-pipelined 4-phase schedule: every MFMA cluster consumes fragments
// ds_read >= 1 phase EARLIER, so MFMA never waits on its own phase's reads.
// No manual lgkm waits: the compiler's dependency-driven counted lgkmcnt(N)
// implements the lookahead (fragments are plain compiler-visible loads).
// 1 block/CU (128 KB LDS) -> no cross-block overlap exists; this in-wave
// ILP is the only way to overlap the LDS pipe (~770 cyc/tile) and barriers
// under the MFMA pipe (~2480 cyc/tile).
//
// Per tile T (cur = buf[T&1], liveness ping-pongs bP/bQ across tiles):
//   enter: A0 in aA, B0 in bP (read during T-1's P4)
//   P1: read B1 -> bQ     | MFMA Q00(aA,bP)         [aA,bP from prev phase]
//   P2: read A1 -> aB     | MFMA Q01(aA,bQ)         [aA dead after]
//   P3:                     MFMA Q11(aB,bQ)         [bQ dead after]
//   vmcnt(0) + s_barrier  -- retires T+1's stages (issued at T-1's P4,
//        ~2500 cyc earlier -> free) = publish buf^1; also proves all waves
//        done reading cur (their reads completed before their P3 MFMAs).
//   P4: read A0',B0' of T+1 from buf^1 -> aA,bQ | stage T+2 -> cur |
//       MFMA Q10(aB,bP)   [bP,aB dead after]
//   exit: B0 of next tile is in bQ -> next tile swaps bP/bQ roles.
// Barriers: 2/tile. XOR chunk swizzle + epilogue layout: verified (R2/R3).
// ---------------------------------------------------------------------------
#define GL2LDS(g, l) \
    __builtin_amdgcn_global_load_lds( \
        (const __attribute__((address_space(1))) void*)(g), \
        (__attribute__((address_space(3))) void*)(l), 16, 0, 0)

__global__ __launch_bounds__(512, 2) void gemm_bt(
    const unsigned short* __restrict__ A,
    const unsigned short* __restrict__ B,
    float* __restrict__ C)
{
    __shared__ __align__(16) unsigned short As[2][256 * BK];   // 2 x 32 KB
    __shared__ __align__(16) unsigned short Bs[2][256 * BK];   // 2 x 32 KB

    const int tid  = threadIdx.x;
    const int wv   = tid >> 6;         // 0..7
    const int lane = tid & 63;
    const int wm   = wv >> 2;          // 0..1  (M half)
    const int wn   = wv & 3;           // 0..3  (N quarter)

    const int bid = blockIdx.x;
    const int wg  = (bid & 7) * 32 + (bid >> 3);   // XCD-chunked remap
    const int m0  = (wg >> 2) * 256;               // 64 m-blocks
    const int n0  = (wg & 3) * 256;                // 4 n-blocks

    // staging: per half-tile (128 rows), wave covers 16 rows as 2 loads of
    // 8 rows; lane -> row lane>>3, chunk (lane&7)^(lane>>3) (XOR swizzle).
    const int srow8 = lane >> 3;
    const int schk  = (lane & 7) ^ srow8;
    const char* ag = (const char*)A +
        ((size_t)(m0 + wv * 16 + srow8) * GK + schk * 8) * 2;
    const char* bg = (const char*)B +
        ((size_t)(n0 + wv * 16 + srow8) * GK + schk * 8) * 2;
    const size_t ROW8 = (size_t)8 * GK * 2;     // 8 rows in global bytes
    const size_t HALF = (size_t)128 * GK * 2;   // 128 rows in global bytes

#define STAGE_A(buf, half, ko) do { \
    GL2LDS(ag + (ko) + (half) * HALF,        (char*)As[buf] + ((half) * 128 + wv * 16) * 128); \
    GL2LDS(ag + (ko) + (half) * HALF + ROW8, (char*)As[buf] + ((half) * 128 + wv * 16 + 8) * 128); \
} while (0)
#define STAGE_B(buf, half, ko) do { \
    GL2LDS(bg + (ko) + (half) * HALF,        (char*)Bs[buf] + ((half) * 128 + wv * 16) * 128); \
    GL2LDS(bg + (ko) + (half) * HALF + ROW8, (char*)Bs[buf] + ((half) * 128 + wv * 16 + 8) * 128); \
} while (0)
#define STAGE_ALL(buf, ko) do { \
    STAGE_A(buf, 0, ko); STAGE_A(buf, 1, ko); \
    STAGE_B(buf, 0, ko); STAGE_B(buf, 1, ko); \
} while (0)

    // fragment read coordinates (verified layout)
    const int rr  = lane & 15;
    const int fsw = lane & 7;
    const int cc  = lane >> 4;
#define CHOFF(s) ((((s) * 4 + cc) ^ fsw) * 16)
    // read a 4-frag A column (half mh) / 2-frag B column (half nh), both s
#define RD_A(dst, Pt, mh) do { \
    _Pragma("unroll") \
    for (int s_ = 0; s_ < 2; ++s_) \
        _Pragma("unroll") \
        for (int i_ = 0; i_ < 4; ++i_) \
            dst[s_][i_] = *(const bf16x8*)((Pt) + \
                (wm * 128 + (mh) * 64 + i_ * 16 + rr) * 128 + CHOFF(s_)); \
} while (0)
#define RD_B(dst, Pt, nh) do { \
    _Pragma("unroll") \
    for (int s_ = 0; s_ < 2; ++s_) \
        _Pragma("unroll") \
        for (int j_ = 0; j_ < 2; ++j_) \
            dst[s_][j_] = *(const bf16x8*)((Pt) + \
                (wn * 64 + (nh) * 32 + j_ * 16 + rr) * 128 + CHOFF(s_)); \
} while (0)

    f32x4 acc[8][4] = {};

#define MFMA16(AF, BF, I0, J0) do { \
    __builtin_amdgcn_s_setprio(1); \
    _Pragma("unroll") \
    for (int s_ = 0; s_ < 2; ++s_) \
        _Pragma("unroll") \
        for (int i_ = 0; i_ < 4; ++i_) \
            _Pragma("unroll") \
            for (int j_ = 0; j_ < 2; ++j_) \
                acc[(I0) + i_][(J0) + j_] = __builtin_amdgcn_mfma_f32_16x16x32_bf16( \
                    AF[s_][i_], BF[s_][j_], acc[(I0) + i_][(J0) + j_], 0, 0, 0); \
    __builtin_amdgcn_s_setprio(0); \
} while (0)

    bf16x8 aA[2][4], aB[2][4], bP[2][2], bQ[2][2];

    // prologue: stage tiles 0 and 1; wait for tile 0 only (counted vmcnt);
    // preload tile 0's A0,B0 fragments.
    STAGE_ALL(0, 0);
    STAGE_ALL(1, 128);
    asm volatile("s_waitcnt vmcnt(8)" ::: "memory");
    __builtin_amdgcn_s_barrier();
    RD_A(aA, (const char*)As[0], 0);
    RD_B(bP, (const char*)Bs[0], 0);

    // TILE body: BPm holds current B0, BQm gets B1 then next tile's B0.
#define TILE(T, cur, nxt, BPm, BQm, doRead, doStage, ko2) do { \
    const char* At = (const char*)As[cur]; \
    const char* Bt = (const char*)Bs[cur]; \
    /* P1 */ \
    RD_B(BQm, Bt, 1); \
    MFMA16(aA, BPm, 0, 0); \
    /* P2 */ \
    RD_A(aB, At, 1); \
    MFMA16(aA, BQm, 0, 2); \
    /* P3 */ \
    MFMA16(aB, BQm, 4, 2); \
    asm volatile("s_waitcnt vmcnt(0)" ::: "memory"); \
    __builtin_amdgcn_s_barrier(); \
    __builtin_amdgcn_sched_barrier(0); \
    /* P4 */ \
    if (doRead) { \
        const char* An = (const char*)As[nxt]; \
        const char* Bn = (const char*)Bs[nxt]; \
        RD_A(aA, An, 0); \
        RD_B(BQm, Bn, 0); \
    } \
    if (doStage) STAGE_ALL(cur, ko2); \
    MFMA16(aB, BPm, 4, 0); \
} while (0)

#pragma unroll 1
    for (int tt = 0; tt < NT / 2; ++tt) {
        const bool nl = (tt < NT / 2 - 1);     // not last iteration
        // tile 2tt   (cur=0): reads of T+1 always real; stage T+2 if nl
        TILE(2 * tt, 0, 1, bP, bQ, true, nl, (size_t)(2 * tt + 2) * 128);
        // tile 2tt+1 (cur=1): reads+stage real if nl
        TILE(2 * tt + 1, 1, 0, bQ, bP, nl, nl, (size_t)(2 * tt + 3) * 128);
    }

    // epilogue: C/D layout col = lane&15, row = (lane>>4)*4 + reg
    const int cn = lane & 15;
    const int rb = (lane >> 4) * 4;
#pragma unroll
    for (int i = 0; i < 8; ++i)
#pragma unroll
        for (int j = 0; j < 4; ++j)
#pragma unroll
            for (int r = 0; r < 4; ++r) {
                const int m = m0 + wm * 128 + i * 16 + rb + r;
                const int n = n0 + wn * 64 + j * 16 + cn;
                C[(size_t)m * GN + n] = acc[i][j][r];
            }
}

// ---------------------------------------------------------------------------
extern "C" void kernel_launch(void* const* d_in, const int* in_sizes, int n_in,
                              void* d_out, int out_size, void* d_ws, size_t ws_size,
                              hipStream_t stream) {
    const float* x  = (const float*)d_in[0];
    const float* ry = (const float*)d_in[1];
    const float* w1 = (const float*)d_in[2];
    const float* w2 = (const float*)d_in[3];
    float* out = (float*)d_out;

    unsigned short* h   = (unsigned short*)d_ws;                       // 128 MiB
    unsigned short* w2b = (unsigned short*)((char*)d_ws +
                           (size_t)M_TOK * FFN * sizeof(unsigned short));
    // w1cT (160 KB) overlays the w2b region: consumed before conv_w2 writes.
    float* w1cT = (float*)w2b;

    prep_w1<<<dim3(FFN / 256), 256, 0, stream>>>(w1, ry, w1cT);
    compute_h<<<dim3(512, 2), 256, 0, stream>>>(x, w1cT, h);
    conv_w2<<<dim3((EMBED * FFN) / (256 * 8)), 256, 0, stream>>>(w2, w2b);
    gemm_bt<<<dim3(256), 512, 0, stream>>>(h, w2b, out);
}